// Round 8
// baseline (400.229 us; speedup 1.0000x reference)
//
#include <hip/hip_runtime.h>

#define T_ 128
#define B_ 4096
#define N_ (T_*B_)
#define H_ 128
#define FEAT_ 96
#define K_ 224
#define G4H_ 512
#define L2E 1.4426950408889634f

typedef __attribute__((ext_vector_type(8))) short short8;   // 8 bf16 = 4 VGPRs
typedef __attribute__((ext_vector_type(4))) short short4v;  // 4 bf16 = 2 VGPRs
typedef __attribute__((ext_vector_type(4))) float f32x4;

// Barrier with LDS-only visibility (global ops stay in flight).
__device__ __forceinline__ void bar_lgkm() {
    asm volatile("s_waitcnt lgkmcnt(0)\n\ts_barrier" ::: "memory");
}

// native bf16 convert (RNE), 1 instr
__device__ __forceinline__ short f2bf(float f) {
    unsigned r;
    asm("v_cvt_pk_bf16_f32 %0, %1, %2" : "=v"(r) : "v"(f), "v"(f));
    return (short)(r & 0xffff);
}
__device__ __forceinline__ short4v pack4relu(const f32x4 a) {
    const float x0 = fmaxf(a[0], 0.f), x1 = fmaxf(a[1], 0.f);
    const float x2 = fmaxf(a[2], 0.f), x3 = fmaxf(a[3], 0.f);
    unsigned r01, r23;
    asm("v_cvt_pk_bf16_f32 %0, %1, %2" : "=v"(r01) : "v"(x0), "v"(x1));
    asm("v_cvt_pk_bf16_f32 %0, %1, %2" : "=v"(r23) : "v"(x2), "v"(x3));
    uint2 u; u.x = r01; u.y = r23;
    return __builtin_bit_cast(short4v, u);
}

// feats stored in MFMA-fragment order per 16-sample group:
// featsb[ ((t*256 + b/16)*3 + kk)*512 + L*8 + j ]
#define FBASE(t, grp, kk) ((((size_t)(t) * 256 + (grp)) * 3 + (kk)) * 512)

// ---------------- prep: pack all weights into bf16 MFMA-fragment order ----------------
__global__ __launch_bounds__(256) void prep_kernel(
    const float* __restrict__ Wih, const float* __restrict__ Whh,
    const float* __restrict__ bih, const float* __restrict__ bhh,
    const float* __restrict__ W1, const float* __restrict__ W2,
    const float* __restrict__ W3, const float* __restrict__ W4,
    short* __restrict__ Wtp, float* __restrict__ bias,
    short* __restrict__ W1p, short* __restrict__ W2p,
    short* __restrict__ W3p, short* __restrict__ W4p)
{
    int idx = blockIdx.x * 256 + threadIdx.x;
    if (idx < 114688) {                     // LSTM combined [224][512]
        int j = idx & 7, L = (idx >> 3) & 63, r = idx >> 9;
        int kk = r % 7, n = r / 7;
        int k = kk * 32 + ((L >> 4) << 3) + j;
        int g = (n << 4) + (L & 15);
        float v = (k < FEAT_) ? Wih[g * FEAT_ + k] : Whh[g * H_ + (k - FEAT_)];
        float s = (n >= 16 && n < 24) ? (2.0f * L2E) : L2E;   // g gate tiles: n 16..23
        Wtp[idx] = f2bf(v * s);
        return;
    }
    int e = idx - 114688;
    if (e < 8192) {                         // W1 [25,256] * (1/255), zero-pad k>=25
        int j = e & 7, L = (e >> 3) & 63, nt = e >> 9;
        int k = ((L >> 4) << 3) + j;
        int o = nt * 16 + (L & 15);
        W1p[e] = (k < 25) ? f2bf(W1[k * 256 + o] * (1.0f / 255.0f)) : (short)0;
        return;
    }
    e -= 8192;
    if (e < 65536) {                        // W2 [256,256]
        int j = e & 7, L = (e >> 3) & 63, f = e >> 9;
        int kk = f & 7, nt = f >> 3;
        int k = kk * 32 + ((L >> 4) << 3) + j;
        W2p[e] = f2bf(W2[k * 256 + nt * 16 + (L & 15)]);
        return;
    }
    e -= 65536;
    if (e < 32768) {                        // W3 [256,128]
        int j = e & 7, L = (e >> 3) & 63, f = e >> 9;
        int kk = f & 7, nt = f >> 3;
        int k = kk * 32 + ((L >> 4) << 3) + j;
        W3p[e] = f2bf(W3[k * 128 + nt * 16 + (L & 15)]);
        return;
    }
    e -= 32768;
    if (e < 4096) {                         // W4 [128,32]
        int j = e & 7, L = (e >> 3) & 63, f = e >> 9;
        int kk = f & 3, nt = f >> 2;
        int k = kk * 32 + ((L >> 4) << 3) + j;
        W4p[e] = f2bf(W4[k * 32 + nt * 16 + (L & 15)]);
        return;
    }
    e -= 4096;
    if (e < 512) {
        float s = ((e >> 7) == 2) ? (2.0f * L2E) : L2E;       // gate 2 = g
        bias[e] = (bih[e] + bhh[e]) * s;
    }
}

// ---------------- persistent MFMA encoder v3: 64-sample tiles + fused loc/energy -----
// (unchanged from previous round)
__global__ __launch_bounds__(512, 1) void enc_kernel(
    const float* __restrict__ image,
    const float* __restrict__ location, const float* __restrict__ energy,
    const float* __restrict__ Wl, const float* __restrict__ bl,
    const float* __restrict__ We, const float* __restrict__ be,
    const short* __restrict__ W1p, const float* __restrict__ b1,
    const short* __restrict__ W2p, const float* __restrict__ b2,
    const short* __restrict__ W3p, const float* __restrict__ b3,
    const short* __restrict__ W4p, const float* __restrict__ b4,
    short* __restrict__ featsb)
{
    __shared__ __align__(16) float Raw[2][1600];    // raw image tile (64 samples x 25)
    __shared__ __align__(16) float LocE[2][192];    // loc(128) | energy(64) per tile
    __shared__ float C[160];                        // Wl[64] | bl[32] | We[32] | be[32]
    __shared__ __align__(16) short In[4 * 512];     // L1 input frags [st][64][8]
    __shared__ __align__(16) short AA[4 * 8 * 512]; // L1 out frags  [st][kk][64][8]
    __shared__ __align__(16) short AB[4 * 8 * 512]; // L2 out frags
    __shared__ __align__(16) short AC[4 * 4 * 512]; // L3 out frags
    const int tid  = threadIdx.x;
    const int lane = tid & 63, wv = tid >> 6;
    const int col  = lane & 15, quad = lane >> 4;

    // ---- register-resident weights & biases
    short8 w1r[2], w2r[2][8], w3r[8], w4r[4];
    #pragma unroll
    for (int i = 0; i < 2; i++)
        w1r[i] = *(const short8*)&W1p[((wv + 8 * i) * 64 + lane) * 8];
    #pragma unroll
    for (int i = 0; i < 2; i++)
        #pragma unroll
        for (int kk = 0; kk < 8; kk++)
            w2r[i][kk] = *(const short8*)&W2p[(((wv + 8 * i) * 8 + kk) * 64 + lane) * 8];
    #pragma unroll
    for (int kk = 0; kk < 8; kk++)
        w3r[kk] = *(const short8*)&W3p[((wv * 8 + kk) * 64 + lane) * 8];
    #pragma unroll
    for (int kk = 0; kk < 4; kk++)
        w4r[kk] = *(const short8*)&W4p[(((wv & 1) * 4 + kk) * 64 + lane) * 8];
    float4 b1r[2], b2r[2];
    #pragma unroll
    for (int i = 0; i < 2; i++) {
        b1r[i] = *(const float4*)(b1 + (wv + 8 * i) * 16 + quad * 4);
        b2r[i] = *(const float4*)(b2 + (wv + 8 * i) * 16 + quad * 4);
    }
    const float4 b3r = *(const float4*)(b3 + wv * 16 + quad * 4);
    const float4 b4r = *(const float4*)(b4 + (wv & 1) * 16 + quad * 4);

    // loc/energy encoder constants -> LDS (visible after prologue barrier)
    if (tid < 160) {
        float v;
        if (tid < 64)       v = Wl[tid];
        else if (tid < 96)  v = bl[tid - 64];
        else if (tid < 128) v = We[tid - 96];
        else                v = be[tid - 128];
        C[tid] = v;
    }

    const bool ld = tid < 400;                      // Raw stagers
    const int le = tid - 400;                       // LocE stagers: 0..47
    float4 ir = {0.f, 0.f, 0.f, 0.f};
    float4 lr = {0.f, 0.f, 0.f, 0.f};

    // fragify indices: 512 threads x short4v cover 4 st x 64 L x 8 j
    const int fj0 = (tid & 1) * 4;
    const int fL  = (tid >> 1) & 63;
    const int fst = tid >> 7;
    const int fs  = fst * 16 + (fL & 15);
    const int fkb = (fL >> 4) * 8 + fj0;

    // loc-feature worker: computes the kk=1,2 fragments for tile tl from LocE[buf].
    auto LOCF = [&](int tl, int buf) {
        const int bi  = tid & 15;
        const int Lhi = (tid >> 4) & 3;
        const int stx = (tid >> 6) & 3;
        const int kkx = tid >> 8;
        const int s   = stx * 16 + bi;
        const float lx = LocE[buf][2 * s]     * 0.1f;
        const float ly = LocE[buf][2 * s + 1] * 0.1f;
        const float ev = LocE[buf][128 + s]   * (1.0f / 200.0f);
        const int t4l  = tl >> 6;
        const int grpl = (tl & 63) * 4 + stx;
        short8 v;
        #pragma unroll
        for (int j = 0; j < 8; j++) {
            const int kl = Lhi * 8 + j;
            float val;
            if (kkx == 0) val = fmaf(lx, C[kl], fmaf(ly, C[32 + kl], C[64 + kl]));
            else          val = fmaf(ev, C[96 + kl], C[128 + kl]);
            v[j] = f2bf(val);
        }
        *(short8*)&featsb[FBASE(t4l, grpl, 1 + kkx) + (Lhi * 16 + bi) * 8] = v;
    };

    // prologue: stage tile(blockIdx) raw+loc; prefetch tile+256; fragify + loc-feats
    if (ld) {
        *(float4*)&Raw[0][4 * tid] = *(const float4*)(image + (size_t)blockIdx.x * 1600 + 4 * tid);
        ir = *(const float4*)(image + (size_t)(blockIdx.x + 256) * 1600 + 4 * tid);
    } else if (le < 48) {
        const float* s0 = (le < 32) ? (location + (size_t)blockIdx.x * 128 + 4 * le)
                                    : (energy   + (size_t)blockIdx.x * 64  + 4 * (le - 32));
        const float* s1 = (le < 32) ? (location + (size_t)(blockIdx.x + 256) * 128 + 4 * le)
                                    : (energy   + (size_t)(blockIdx.x + 256) * 64  + 4 * (le - 32));
        *(float4*)&LocE[0][4 * le] = *(const float4*)s0;
        lr = *(const float4*)s1;
    }
    bar_lgkm();
    {
        short4v v;
        #pragma unroll
        for (int jj = 0; jj < 4; jj++) {
            const int kx = fkb + jj;
            v[jj] = (kx < 25) ? f2bf(Raw[0][fs * 25 + kx]) : (short)0;
        }
        *(short4v*)&In[(fst * 64 + fL) * 8 + fj0] = v;
    }
    LOCF(blockIdx.x, 0);

    for (int it = 0; it < 32; it++) {
        const int nxt = (it & 1) ^ 1;
        const int tile = it * 256 + blockIdx.x;          // 64-sample tile id, 0..8191
        // stage next tile's raw+loc, prefetch tile+2
        if (it + 1 < 32) {
            if (ld) *(float4*)&Raw[nxt][4 * tid] = ir;
            else if (le < 48) *(float4*)&LocE[nxt][4 * le] = lr;
        }
        if (it + 2 < 32) {
            if (ld) ir = *(const float4*)(image + (size_t)(tile + 512) * 1600 + 4 * tid);
            else if (le < 48) {
                const float* s1 = (le < 32) ? (location + (size_t)(tile + 512) * 128 + 4 * le)
                                            : (energy   + (size_t)(tile + 512) * 64  + 4 * (le - 32));
                lr = *(const float4*)s1;
            }
        }
        bar_lgkm();        // b0: In(tile) + Raw/LocE[nxt] visible; prefetches in flight

        // ---- L1: K=32 -> 256; wave owns nt {wv, wv+8}, st 0..3
        {
            short8 bx[4];
            #pragma unroll
            for (int st = 0; st < 4; st++) bx[st] = *(const short8*)&In[(st * 64 + lane) * 8];
            #pragma unroll
            for (int i = 0; i < 2; i++) {
                const int nt = wv + 8 * i;
                #pragma unroll
                for (int st = 0; st < 4; st++) {
                    f32x4 acc = (f32x4){b1r[i].x, b1r[i].y, b1r[i].z, b1r[i].w};
                    acc = __builtin_amdgcn_mfma_f32_16x16x32_bf16(w1r[i], bx[st], acc, 0, 0, 0);
                    *(short4v*)&AA[((st * 8 + (nt >> 1)) * 64 + ((((nt & 1) << 1) + (quad >> 1)) << 4) + col) * 8 + (quad & 1) * 4]
                        = pack4relu(acc);
                }
            }
        }
        bar_lgkm();        // b1

        // ---- L2: 256 -> 256 : AA -> AB
        {
            f32x4 acc[2][4];
            #pragma unroll
            for (int i = 0; i < 2; i++)
                #pragma unroll
                for (int st = 0; st < 4; st++)
                    acc[i][st] = (f32x4){b2r[i].x, b2r[i].y, b2r[i].z, b2r[i].w};
            #pragma unroll
            for (int kk = 0; kk < 8; kk++) {
                short8 bx[4];
                #pragma unroll
                for (int st = 0; st < 4; st++)
                    bx[st] = *(const short8*)&AA[((st * 8 + kk) * 64 + lane) * 8];
                #pragma unroll
                for (int i = 0; i < 2; i++)
                    #pragma unroll
                    for (int st = 0; st < 4; st++)
                        acc[i][st] = __builtin_amdgcn_mfma_f32_16x16x32_bf16(w2r[i][kk], bx[st], acc[i][st], 0, 0, 0);
            }
            #pragma unroll
            for (int i = 0; i < 2; i++) {
                const int nt = wv + 8 * i;
                #pragma unroll
                for (int st = 0; st < 4; st++)
                    *(short4v*)&AB[((st * 8 + (nt >> 1)) * 64 + ((((nt & 1) << 1) + (quad >> 1)) << 4) + col) * 8 + (quad & 1) * 4]
                        = pack4relu(acc[i][st]);
            }
        }
        bar_lgkm();        // b2

        // ---- L3: 256 -> 128 : AB -> AC; wave owns nt=wv
        {
            f32x4 acc[4];
            #pragma unroll
            for (int st = 0; st < 4; st++) acc[st] = (f32x4){b3r.x, b3r.y, b3r.z, b3r.w};
            #pragma unroll
            for (int kk = 0; kk < 8; kk++) {
                #pragma unroll
                for (int st = 0; st < 4; st++) {
                    const short8 bx = *(const short8*)&AB[((st * 8 + kk) * 64 + lane) * 8];
                    acc[st] = __builtin_amdgcn_mfma_f32_16x16x32_bf16(w3r[kk], bx, acc[st], 0, 0, 0);
                }
            }
            const int nt = wv;
            #pragma unroll
            for (int st = 0; st < 4; st++)
                *(short4v*)&AC[((st * 4 + (nt >> 1)) * 64 + ((((nt & 1) << 1) + (quad >> 1)) << 4) + col) * 8 + (quad & 1) * 4]
                    = pack4relu(acc[st]);
        }
        bar_lgkm();        // b3

        // ---- L4: all 8 waves, one (nt, st) each; then loc-feats + fragify (tile it+1)
        {
            const int nt = wv & 1, st = wv >> 1;
            f32x4 acc = (f32x4){b4r.x, b4r.y, b4r.z, b4r.w};
            #pragma unroll
            for (int kk = 0; kk < 4; kk++) {
                const short8 bx = *(const short8*)&AC[((st * 4 + kk) * 64 + lane) * 8];
                acc = __builtin_amdgcn_mfma_f32_16x16x32_bf16(w4r[kk], bx, acc, 0, 0, 0);
            }
            const int t4 = tile >> 6;                       // 64 tiles per timestep
            const int grp = (tile & 63) * 4 + st;
            *(short4v*)&featsb[FBASE(t4, grp, 0) + (((nt << 1) + (quad >> 1)) * 16 + col) * 8 + (quad & 1) * 4]
                = pack4relu(acc);
        }
        if (it + 1 < 32) {
            LOCF(tile + 256, nxt);
            short4v v;
            #pragma unroll
            for (int jj = 0; jj < 4; jj++) {
                const int kx = fkb + jj;
                v[jj] = (kx < 25) ? f2bf(Raw[nxt][fs * 25 + kx]) : (short)0;
            }
            *(short4v*)&In[(fst * 64 + fL) * 8 + fj0] = v;
        }
    }
}

// ---------------- MFMA LSTM v8: head folded into the main GEMM ----------------------
// Head(t-1) is computed DURING step t's gate GEMM on wave (t-1)&7, reusing the h
// fragments (af_raw, unmasked) already loaded for the gates — zero extra LDS traffic,
// +4 MFMA on one wave. The post-barrier head phase (8 ds_read_b128 + 4 MFMA straggler
// that delayed all 8 waves every step) is deleted; head weights live in 16 VGPRs.
__global__ __launch_bounds__(512, 1) void lstm_kernel(
    const short* __restrict__ featsb, const int* __restrict__ done,
    const float* __restrict__ h0, const float* __restrict__ c0,
    const short* __restrict__ Wtp, const float* __restrict__ bias,
    const float* __restrict__ Wa, const float* __restrict__ ba,
    const float* __restrict__ Wc, const float* __restrict__ bc,
    float* __restrict__ out)
{
    __shared__ __align__(16) short Hb[2][4 * 64 * 8];   // h frags [buf][kk2][64][8]
    __shared__ float Ml[T_ * 16];                       // reset masks

    const int tid = threadIdx.x;
    const int r0 = blockIdx.x * 16;
    const int grp = r0 >> 4;
    const int lane = tid & 63;
    const int wv = tid >> 6;
    const int col = lane & 15;
    const int quad = lane >> 4;
    const int u = (wv << 4) + col;

    // register-resident LSTM weights: wave wv owns n-tiles {wv, wv+8, wv+16, wv+24}
    short8 wtr[4][7];
    #pragma unroll
    for (int g = 0; g < 4; g++)
        #pragma unroll
        for (int kk = 0; kk < 7; kk++)
            wtr[g][kk] = *(const short8*)&Wtp[((size_t)((wv + 8 * g) * 7 + kk) * 64 + lane) * 8];

    // head weight B-frags -> registers (every wave; ownership rotates per step)
    // hwr[kk2][j] = (n<6 ? Wa[k*6+n] : n==6 ? Wc[k] : 0), k=kk2*32+((lane>>4)<<3)+j, n=lane&15
    short8 hwr[4];
    {
        const int n = lane & 15;
        #pragma unroll
        for (int kk2 = 0; kk2 < 4; kk2++) {
            short8 v;
            #pragma unroll
            for (int j = 0; j < 8; j++) {
                const int k = kk2 * 32 + ((lane >> 4) << 3) + j;
                const float w = (n < 6) ? Wa[k * 6 + n] : (n == 6 ? Wc[k] : 0.0f);
                v[j] = f2bf(w);
            }
            hwr[kk2] = v;
        }
    }
    // reset masks for all T
    for (int idx = tid; idx < T_ * 16; idx += 512)
        Ml[idx] = 1.0f - (float)done[(size_t)(idx >> 4) * B_ + r0 + (idx & 15)];

    // init: c masked by done[0]; h0 UNMASKED into Hb[0] (mask applied at GEMM read)
    const int kk2h = wv >> 1;
    const int Lhi_h = ((wv & 1) << 1) | (col >> 3);
    const int jh = col & 7;
    f32x4 c;
    #pragma unroll
    for (int r = 0; r < 4; r++) {
        const int s = (quad << 2) + r;
        const float m = 1.0f - (float)done[r0 + s];
        c[r] = c0[(size_t)(r0 + s) * H_ + u] * m;
        Hb[0][(kk2h * 64 + Lhi_h * 16 + s) * 8 + jh] = f2bf(h0[(size_t)(r0 + s) * H_ + u]);
    }
    const float bi0 = bias[((wv +  0) << 4) + col];
    const float bi1 = bias[((wv +  8) << 4) + col];
    const float bi2 = bias[((wv + 16) << 4) + col];
    const float bi3 = bias[((wv + 24) << 4) + col];
    const float hb = (col < 6) ? ba[col] : (col == 6 ? bc[0] : 0.0f);

    // x prefetch banks (t-loop unrolled by 2) + x-part gate accumulators
    short8 xa[3], xb[3];
    #pragma unroll
    for (int kk = 0; kk < 3; kk++) {
        xa[kk] = *(const short8*)&featsb[FBASE(0, grp, kk) + lane * 8];
        xb[kk] = *(const short8*)&featsb[FBASE(1, grp, kk) + lane * 8];
    }
    // accX for t=0 from xa (xa regs free afterwards)
    f32x4 axA[4], axB[4];
    axA[0] = (f32x4){bi0, bi0, bi0, bi0};
    axA[1] = (f32x4){bi1, bi1, bi1, bi1};
    axA[2] = (f32x4){bi2, bi2, bi2, bi2};
    axA[3] = (f32x4){bi3, bi3, bi3, bi3};
    #pragma unroll
    for (int kk = 0; kk < 3; kk++) {
        axA[0] = __builtin_amdgcn_mfma_f32_16x16x32_bf16(xa[kk], wtr[0][kk], axA[0], 0, 0, 0);
        axA[1] = __builtin_amdgcn_mfma_f32_16x16x32_bf16(xa[kk], wtr[1][kk], axA[1], 0, 0, 0);
        axA[2] = __builtin_amdgcn_mfma_f32_16x16x32_bf16(xa[kk], wtr[2][kk], axA[2], 0, 0, 0);
        axA[3] = __builtin_amdgcn_mfma_f32_16x16x32_bf16(xa[kk], wtr[3][kk], axA[3], 0, 0, 0);
    }
    bar_lgkm();

    // STEP(t): Xload gets feats(t+2); Xuse feeds accX for t+1.
    // Head(t-1) folds into the h-MFMA loop on wave (t-1)&7 via af_raw + hwr.
    auto STEP = [&](int t, int cur, short8* Xload, short8* Xuse, f32x4* axT, f32x4* axN) {
        const int nxt = cur ^ 1;
        if (t + 2 < T_) {
            #pragma unroll
            for (int kk = 0; kk < 3; kk++)
                Xload[kk] = *(const short8*)&featsb[FBASE(t + 2, grp, kk) + lane * 8];
        }
        const float mcol = Ml[t * 16 + col];
        const bool headw = (t >= 1) && (wv == ((t - 1) & 7));
        // h-part: chain depth 4, seeded from accX (computed last step)
        f32x4 acc0 = axT[0], acc1 = axT[1], acc2 = axT[2], acc3 = axT[3];
        f32x4 ha = {hb, hb, hb, hb};
        #pragma unroll
        for (int kk2 = 0; kk2 < 4; kk2++) {
            const short8 af_raw = *(const short8*)&Hb[cur][(kk2 * 64 + lane) * 8];
            short8 af = af_raw;
            if (mcol == 0.0f) af = (short8){0,0,0,0,0,0,0,0};
            acc0 = __builtin_amdgcn_mfma_f32_16x16x32_bf16(af, wtr[0][3 + kk2], acc0, 0, 0, 0);
            acc1 = __builtin_amdgcn_mfma_f32_16x16x32_bf16(af, wtr[1][3 + kk2], acc1, 0, 0, 0);
            acc2 = __builtin_amdgcn_mfma_f32_16x16x32_bf16(af, wtr[2][3 + kk2], acc2, 0, 0, 0);
            acc3 = __builtin_amdgcn_mfma_f32_16x16x32_bf16(af, wtr[3][3 + kk2], acc3, 0, 0, 0);
            if (headw)
                ha = __builtin_amdgcn_mfma_f32_16x16x32_bf16(af_raw, hwr[kk2], ha, 0, 0, 0);
        }
        // head(t-1) store: global, flies across the lgkm-only barrier
        if (headw && col < 7) {
            #pragma unroll
            for (int r = 0; r < 4; r++) {
                const int s = (quad << 2) + r;
                out[((size_t)(t - 1) * B_ + r0 + s) * 7 + col] = ha[r];
            }
        }
        // x-part for t+1: independent MFMAs, execute during the VALU section below
        f32x4 n0 = (f32x4){bi0, bi0, bi0, bi0};
        f32x4 n1 = (f32x4){bi1, bi1, bi1, bi1};
        f32x4 n2 = (f32x4){bi2, bi2, bi2, bi2};
        f32x4 n3 = (f32x4){bi3, bi3, bi3, bi3};
        #pragma unroll
        for (int kk = 0; kk < 3; kk++) {
            n0 = __builtin_amdgcn_mfma_f32_16x16x32_bf16(Xuse[kk], wtr[0][kk], n0, 0, 0, 0);
            n1 = __builtin_amdgcn_mfma_f32_16x16x32_bf16(Xuse[kk], wtr[1][kk], n1, 0, 0, 0);
            n2 = __builtin_amdgcn_mfma_f32_16x16x32_bf16(Xuse[kk], wtr[2][kk], n2, 0, 0, 0);
            n3 = __builtin_amdgcn_mfma_f32_16x16x32_bf16(Xuse[kk], wtr[3][kk], n3, 0, 0, 0);
        }
        axN[0] = n0; axN[1] = n1; axN[2] = n2; axN[3] = n3;
        // cell update: rcp-merged form, 5 exp2 + 2 rcp per element
        float4 mn = {1.f, 1.f, 1.f, 1.f};
        if (t < T_ - 1) mn = *(const float4*)&Ml[(t + 1) * 16 + (quad << 2)];
        #pragma unroll
        for (int r = 0; r < 4; r++) {
            const float ei = __builtin_amdgcn_exp2f(-acc0[r]);     // i gate
            const float ef = __builtin_amdgcn_exp2f(-acc1[r]);     // f gate
            const float eg = __builtin_amdgcn_exp2f(-acc2[r]);     // g gate (2x pre-scale)
            const float eo = __builtin_amdgcn_exp2f(-acc3[r]);     // o gate
            const float Ai = 1.0f + ei, Bf = 1.0f + ef;
            const float Gg = 1.0f + eg, Do = 1.0f + eo;
            const float AG = Ai * Gg;
            const float num = fmaf(c[r], AG, (1.0f - eg) * Bf);
            const float cn = num * __builtin_amdgcn_rcpf(AG * Bf);
            const float et = __builtin_amdgcn_exp2f(-2.0f * L2E * cn);
            const float h = (1.0f - et) * __builtin_amdgcn_rcpf(Do * (1.0f + et));
            c[r] = cn * ((&mn.x)[r]);
            Hb[nxt][(kk2h * 64 + Lhi_h * 16 + (quad << 2) + r) * 8 + jh] = f2bf(h);
        }
        bar_lgkm();
    };

    for (int t = 0; t < T_; t += 2) {
        STEP(t,     0, xa, xb, axA, axB);
        STEP(t + 1, 1, xb, xa, axB, axA);
    }
    // epilogue head(T-1): h_127 is in Hb[0] (STEP(127): nxt=0, barrier passed)
    if (wv == ((T_ - 1) & 7)) {
        f32x4 ha = {hb, hb, hb, hb};
        #pragma unroll
        for (int kk2 = 0; kk2 < 4; kk2++) {
            const short8 hf = *(const short8*)&Hb[0][(kk2 * 64 + lane) * 8];
            ha = __builtin_amdgcn_mfma_f32_16x16x32_bf16(hf, hwr[kk2], ha, 0, 0, 0);
        }
        if (col < 7) {
            #pragma unroll
            for (int r = 0; r < 4; r++) {
                const int s = (quad << 2) + r;
                out[((size_t)(T_ - 1) * B_ + r0 + s) * 7 + col] = ha[r];
            }
        }
    }
}

extern "C" void kernel_launch(void* const* d_in, const int* in_sizes, int n_in,
                              void* d_out, int out_size, void* d_ws, size_t ws_size,
                              hipStream_t stream) {
    const float* image    = (const float*)d_in[0];
    const float* location = (const float*)d_in[1];
    const float* energy   = (const float*)d_in[2];
    const int*   done     = (const int*)d_in[3];
    const float* h0       = (const float*)d_in[4];
    const float* c0       = (const float*)d_in[5];
    const float* W1 = (const float*)d_in[6];   const float* b1 = (const float*)d_in[7];
    const float* W2 = (const float*)d_in[8];   const float* b2 = (const float*)d_in[9];
    const float* W3 = (const float*)d_in[10];  const float* b3 = (const float*)d_in[11];
    const float* W4 = (const float*)d_in[12];  const float* b4 = (const float*)d_in[13];
    const float* Wl = (const float*)d_in[14];  const float* bl = (const float*)d_in[15];
    const float* We = (const float*)d_in[16];  const float* be = (const float*)d_in[17];
    const float* Wih = (const float*)d_in[18]; const float* Whh = (const float*)d_in[19];
    const float* bih = (const float*)d_in[20]; const float* bhh = (const float*)d_in[21];
    const float* Wa = (const float*)d_in[22];  const float* ba = (const float*)d_in[23];
    const float* Wc = (const float*)d_in[24];  const float* bc = (const float*)d_in[25];

    char* ws = (char*)d_ws;
    short* Wtp   = (short*)ws;                     // 229376 B
    float* bias  = (float*)(ws + 229376);          // 2048 B
    short* W1p   = (short*)(ws + 231424);          // 16384 B
    short* W2p   = (short*)(ws + 247808);          // 131072 B
    short* W3p   = (short*)(ws + 378880);          // 65536 B
    short* W4p   = (short*)(ws + 444416);          // 8192 B
    short* featsb = (short*)(ws + 452608);         // N*96 bf16 (frag order)
    float* out   = (float*)d_out;

    prep_kernel<<<882, 256, 0, stream>>>(Wih, Whh, bih, bhh, W1, W2, W3, W4,
                                         Wtp, bias, W1p, W2p, W3p, W4p);
    enc_kernel<<<256, 512, 0, stream>>>(image, location, energy, Wl, bl, We, be,
                                        W1p, b1, W2p, b2, W3p, b3, W4p, b4, featsb);
    lstm_kernel<<<B_ / 16, 512, 0, stream>>>(featsb, done, h0, c0, Wtp, bias,
                                             Wa, ba, Wc, bc, out);
}

// Round 9
// 385.868 us; speedup vs baseline: 1.0372x; 1.0372x over previous
//
#include <hip/hip_runtime.h>

#define T_ 128
#define B_ 4096
#define N_ (T_*B_)
#define H_ 128
#define FEAT_ 96
#define K_ 224
#define G4H_ 512
#define L2E 1.4426950408889634f

typedef __attribute__((ext_vector_type(8))) short short8;   // 8 bf16 = 4 VGPRs
typedef __attribute__((ext_vector_type(4))) short short4v;  // 4 bf16 = 2 VGPRs
typedef __attribute__((ext_vector_type(4))) float f32x4;

// Barrier with LDS-only visibility (global ops stay in flight).
__device__ __forceinline__ void bar_lgkm() {
    asm volatile("s_waitcnt lgkmcnt(0)\n\ts_barrier" ::: "memory");
}

// native bf16 convert (RNE), 1 instr
__device__ __forceinline__ short f2bf(float f) {
    unsigned r;
    asm("v_cvt_pk_bf16_f32 %0, %1, %2" : "=v"(r) : "v"(f), "v"(f));
    return (short)(r & 0xffff);
}
__device__ __forceinline__ short4v pack4relu(const f32x4 a) {
    const float x0 = fmaxf(a[0], 0.f), x1 = fmaxf(a[1], 0.f);
    const float x2 = fmaxf(a[2], 0.f), x3 = fmaxf(a[3], 0.f);
    unsigned r01, r23;
    asm("v_cvt_pk_bf16_f32 %0, %1, %2" : "=v"(r01) : "v"(x0), "v"(x1));
    asm("v_cvt_pk_bf16_f32 %0, %1, %2" : "=v"(r23) : "v"(x2), "v"(x3));
    uint2 u; u.x = r01; u.y = r23;
    return __builtin_bit_cast(short4v, u);
}

// feats stored in MFMA-fragment order per 16-sample group:
// featsb[ ((t*256 + b/16)*3 + kk)*512 + L*8 + j ]
#define FBASE(t, grp, kk) ((((size_t)(t) * 256 + (grp)) * 3 + (kk)) * 512)

// ---------------- prep: pack all weights into bf16 MFMA-fragment order ----------------
__global__ __launch_bounds__(256) void prep_kernel(
    const float* __restrict__ Wih, const float* __restrict__ Whh,
    const float* __restrict__ bih, const float* __restrict__ bhh,
    const float* __restrict__ W1, const float* __restrict__ W2,
    const float* __restrict__ W3, const float* __restrict__ W4,
    short* __restrict__ Wtp, float* __restrict__ bias,
    short* __restrict__ W1p, short* __restrict__ W2p,
    short* __restrict__ W3p, short* __restrict__ W4p)
{
    int idx = blockIdx.x * 256 + threadIdx.x;
    if (idx < 114688) {                     // LSTM combined [224][512]
        int j = idx & 7, L = (idx >> 3) & 63, r = idx >> 9;
        int kk = r % 7, n = r / 7;
        int k = kk * 32 + ((L >> 4) << 3) + j;
        int g = (n << 4) + (L & 15);
        float v = (k < FEAT_) ? Wih[g * FEAT_ + k] : Whh[g * H_ + (k - FEAT_)];
        float s = (n >= 16 && n < 24) ? (2.0f * L2E) : L2E;   // g gate tiles: n 16..23
        Wtp[idx] = f2bf(v * s);
        return;
    }
    int e = idx - 114688;
    if (e < 8192) {                         // W1 [25,256] * (1/255), zero-pad k>=25
        int j = e & 7, L = (e >> 3) & 63, nt = e >> 9;
        int k = ((L >> 4) << 3) + j;
        int o = nt * 16 + (L & 15);
        W1p[e] = (k < 25) ? f2bf(W1[k * 256 + o] * (1.0f / 255.0f)) : (short)0;
        return;
    }
    e -= 8192;
    if (e < 65536) {                        // W2 [256,256]
        int j = e & 7, L = (e >> 3) & 63, f = e >> 9;
        int kk = f & 7, nt = f >> 3;
        int k = kk * 32 + ((L >> 4) << 3) + j;
        W2p[e] = f2bf(W2[k * 256 + nt * 16 + (L & 15)]);
        return;
    }
    e -= 65536;
    if (e < 32768) {                        // W3 [256,128]
        int j = e & 7, L = (e >> 3) & 63, f = e >> 9;
        int kk = f & 7, nt = f >> 3;
        int k = kk * 32 + ((L >> 4) << 3) + j;
        W3p[e] = f2bf(W3[k * 128 + nt * 16 + (L & 15)]);
        return;
    }
    e -= 32768;
    if (e < 4096) {                         // W4 [128,32]
        int j = e & 7, L = (e >> 3) & 63, f = e >> 9;
        int kk = f & 3, nt = f >> 2;
        int k = kk * 32 + ((L >> 4) << 3) + j;
        W4p[e] = f2bf(W4[k * 32 + nt * 16 + (L & 15)]);
        return;
    }
    e -= 4096;
    if (e < 512) {
        float s = ((e >> 7) == 2) ? (2.0f * L2E) : L2E;       // gate 2 = g
        bias[e] = (bih[e] + bhh[e]) * s;
    }
}

// ---------------- persistent MFMA encoder v4: skewed 2-tile pipeline -----------------
// 256 blocks x 512 thr x 32 iters; TWO barriers per 64-sample tile (was four).
// Interval A: stage(it+1) | L1(it) | L3(it-1).  Interval B: L2(it) | L4(it-1) |
// LOCF/fragify(it+1).  Buffer liveness: AA W@A(it)->R@B(it); AB W@B(it)->R@A(it+1);
// AC W@A(it)->R@B(it+1) — all single-copy, one barrier apart. loc/energy fused.
__global__ __launch_bounds__(512, 1) void enc_kernel(
    const float* __restrict__ image,
    const float* __restrict__ location, const float* __restrict__ energy,
    const float* __restrict__ Wl, const float* __restrict__ bl,
    const float* __restrict__ We, const float* __restrict__ be,
    const short* __restrict__ W1p, const float* __restrict__ b1,
    const short* __restrict__ W2p, const float* __restrict__ b2,
    const short* __restrict__ W3p, const float* __restrict__ b3,
    const short* __restrict__ W4p, const float* __restrict__ b4,
    short* __restrict__ featsb)
{
    __shared__ __align__(16) float Raw[2][1600];    // raw image tile (64 samples x 25)
    __shared__ __align__(16) float LocE[2][192];    // loc(128) | energy(64) per tile
    __shared__ float C[160];                        // Wl[64] | bl[32] | We[32] | be[32]
    __shared__ __align__(16) short In[4 * 512];     // L1 input frags [st][64][8]
    __shared__ __align__(16) short AA[4 * 8 * 512]; // L1 out frags  [st][kk][64][8]
    __shared__ __align__(16) short AB[4 * 8 * 512]; // L2 out frags
    __shared__ __align__(16) short AC[4 * 4 * 512]; // L3 out frags
    const int tid  = threadIdx.x;
    const int lane = tid & 63, wv = tid >> 6;
    const int col  = lane & 15, quad = lane >> 4;

    // ---- register-resident weights & biases
    short8 w1r[2], w2r[2][8], w3r[8], w4r[4];
    #pragma unroll
    for (int i = 0; i < 2; i++)
        w1r[i] = *(const short8*)&W1p[((wv + 8 * i) * 64 + lane) * 8];
    #pragma unroll
    for (int i = 0; i < 2; i++)
        #pragma unroll
        for (int kk = 0; kk < 8; kk++)
            w2r[i][kk] = *(const short8*)&W2p[(((wv + 8 * i) * 8 + kk) * 64 + lane) * 8];
    #pragma unroll
    for (int kk = 0; kk < 8; kk++)
        w3r[kk] = *(const short8*)&W3p[((wv * 8 + kk) * 64 + lane) * 8];
    #pragma unroll
    for (int kk = 0; kk < 4; kk++)
        w4r[kk] = *(const short8*)&W4p[(((wv & 1) * 4 + kk) * 64 + lane) * 8];
    float4 b1r[2], b2r[2];
    #pragma unroll
    for (int i = 0; i < 2; i++) {
        b1r[i] = *(const float4*)(b1 + (wv + 8 * i) * 16 + quad * 4);
        b2r[i] = *(const float4*)(b2 + (wv + 8 * i) * 16 + quad * 4);
    }
    const float4 b3r = *(const float4*)(b3 + wv * 16 + quad * 4);
    const float4 b4r = *(const float4*)(b4 + (wv & 1) * 16 + quad * 4);

    // loc/energy encoder constants -> LDS (visible after prologue barrier)
    if (tid < 160) {
        float v;
        if (tid < 64)       v = Wl[tid];
        else if (tid < 96)  v = bl[tid - 64];
        else if (tid < 128) v = We[tid - 96];
        else                v = be[tid - 128];
        C[tid] = v;
    }

    const bool ld = tid < 400;                      // Raw stagers
    const int le = tid - 400;                       // LocE stagers: 0..47
    float4 ir = {0.f, 0.f, 0.f, 0.f};
    float4 lr = {0.f, 0.f, 0.f, 0.f};

    // fragify indices: 512 threads x short4v cover 4 st x 64 L x 8 j
    const int fj0 = (tid & 1) * 4;
    const int fL  = (tid >> 1) & 63;
    const int fst = tid >> 7;
    const int fs  = fst * 16 + (fL & 15);
    const int fkb = (fL >> 4) * 8 + fj0;

    // loc-feature worker: computes the kk=1,2 fragments for tile tl from LocE[buf].
    auto LOCF = [&](int tl, int buf) {
        const int bi  = tid & 15;
        const int Lhi = (tid >> 4) & 3;
        const int stx = (tid >> 6) & 3;
        const int kkx = tid >> 8;
        const int s   = stx * 16 + bi;
        const float lx = LocE[buf][2 * s]     * 0.1f;
        const float ly = LocE[buf][2 * s + 1] * 0.1f;
        const float ev = LocE[buf][128 + s]   * (1.0f / 200.0f);
        const int t4l  = tl >> 6;
        const int grpl = (tl & 63) * 4 + stx;
        short8 v;
        #pragma unroll
        for (int j = 0; j < 8; j++) {
            const int kl = Lhi * 8 + j;
            float val;
            if (kkx == 0) val = fmaf(lx, C[kl], fmaf(ly, C[32 + kl], C[64 + kl]));
            else          val = fmaf(ev, C[96 + kl], C[128 + kl]);
            v[j] = f2bf(val);
        }
        *(short8*)&featsb[FBASE(t4l, grpl, 1 + kkx) + (Lhi * 16 + bi) * 8] = v;
    };
    // In-fragify worker for Raw[buf]
    auto FRAG = [&](int buf) {
        short4v v;
        #pragma unroll
        for (int jj = 0; jj < 4; jj++) {
            const int kx = fkb + jj;
            v[jj] = (kx < 25) ? f2bf(Raw[buf][fs * 25 + kx]) : (short)0;
        }
        *(short4v*)&In[(fst * 64 + fL) * 8 + fj0] = v;
    };
    // L3 body for the tile whose AB is current: AB -> AC
    auto L3B = [&]() {
        f32x4 acc[4];
        #pragma unroll
        for (int st = 0; st < 4; st++) acc[st] = (f32x4){b3r.x, b3r.y, b3r.z, b3r.w};
        #pragma unroll
        for (int kk = 0; kk < 8; kk++) {
            #pragma unroll
            for (int st = 0; st < 4; st++) {
                const short8 bx = *(const short8*)&AB[((st * 8 + kk) * 64 + lane) * 8];
                acc[st] = __builtin_amdgcn_mfma_f32_16x16x32_bf16(w3r[kk], bx, acc[st], 0, 0, 0);
            }
        }
        const int nt = wv;
        #pragma unroll
        for (int st = 0; st < 4; st++)
            *(short4v*)&AC[((st * 4 + (nt >> 1)) * 64 + ((((nt & 1) << 1) + (quad >> 1)) << 4) + col) * 8 + (quad & 1) * 4]
                = pack4relu(acc[st]);
    };
    // L4 body: AC -> featsb for tile pt
    auto L4B = [&](int pt) {
        const int nt = wv & 1, st = wv >> 1;
        f32x4 acc = (f32x4){b4r.x, b4r.y, b4r.z, b4r.w};
        #pragma unroll
        for (int kk = 0; kk < 4; kk++) {
            const short8 bx = *(const short8*)&AC[((st * 4 + kk) * 64 + lane) * 8];
            acc = __builtin_amdgcn_mfma_f32_16x16x32_bf16(w4r[kk], bx, acc, 0, 0, 0);
        }
        const int t4 = pt >> 6;
        const int grp = (pt & 63) * 4 + st;
        *(short4v*)&featsb[FBASE(t4, grp, 0) + (((nt << 1) + (quad >> 1)) * 16 + col) * 8 + (quad & 1) * 4]
            = pack4relu(acc);
    };

    // prologue: stage tile0 raw+loc; prefetch tile1; fragify In(0) + loc-feats(0)
    if (ld) {
        *(float4*)&Raw[0][4 * tid] = *(const float4*)(image + (size_t)blockIdx.x * 1600 + 4 * tid);
        ir = *(const float4*)(image + (size_t)(blockIdx.x + 256) * 1600 + 4 * tid);
    } else if (le < 48) {
        const float* s0 = (le < 32) ? (location + (size_t)blockIdx.x * 128 + 4 * le)
                                    : (energy   + (size_t)blockIdx.x * 64  + 4 * (le - 32));
        const float* s1 = (le < 32) ? (location + (size_t)(blockIdx.x + 256) * 128 + 4 * le)
                                    : (energy   + (size_t)(blockIdx.x + 256) * 64  + 4 * (le - 32));
        *(float4*)&LocE[0][4 * le] = *(const float4*)s0;
        lr = *(const float4*)s1;
    }
    bar_lgkm();
    FRAG(0);
    LOCF(blockIdx.x, 0);
    bar_lgkm();     // In(0) visible for L1(0)

    for (int it = 0; it < 32; it++) {
        const int nxt = (it & 1) ^ 1;
        const int tile = it * 256 + blockIdx.x;          // 64-sample tile id
        // ---- interval A: stage(it+1), prefetch(it+2), L1(it), L3(it-1)
        if (it + 1 < 32) {
            if (ld) *(float4*)&Raw[nxt][4 * tid] = ir;
            else if (le < 48) *(float4*)&LocE[nxt][4 * le] = lr;
        }
        if (it + 2 < 32) {
            if (ld) ir = *(const float4*)(image + (size_t)(tile + 512) * 1600 + 4 * tid);
            else if (le < 48) {
                const float* s1 = (le < 32) ? (location + (size_t)(tile + 512) * 128 + 4 * le)
                                            : (energy   + (size_t)(tile + 512) * 64  + 4 * (le - 32));
                lr = *(const float4*)s1;
            }
        }
        // L1(it): In -> AA
        {
            short8 bx[4];
            #pragma unroll
            for (int st = 0; st < 4; st++) bx[st] = *(const short8*)&In[(st * 64 + lane) * 8];
            #pragma unroll
            for (int i = 0; i < 2; i++) {
                const int nt = wv + 8 * i;
                #pragma unroll
                for (int st = 0; st < 4; st++) {
                    f32x4 acc = (f32x4){b1r[i].x, b1r[i].y, b1r[i].z, b1r[i].w};
                    acc = __builtin_amdgcn_mfma_f32_16x16x32_bf16(w1r[i], bx[st], acc, 0, 0, 0);
                    *(short4v*)&AA[((st * 8 + (nt >> 1)) * 64 + ((((nt & 1) << 1) + (quad >> 1)) << 4) + col) * 8 + (quad & 1) * 4]
                        = pack4relu(acc);
                }
            }
        }
        if (it >= 1) L3B();          // L3(it-1): AB -> AC
        bar_lgkm();                  // interval-A barrier

        // ---- interval B: L2(it), L4(it-1), LOCF/fragify(it+1)
        {
            f32x4 acc[2][4];
            #pragma unroll
            for (int i = 0; i < 2; i++)
                #pragma unroll
                for (int st = 0; st < 4; st++)
                    acc[i][st] = (f32x4){b2r[i].x, b2r[i].y, b2r[i].z, b2r[i].w};
            #pragma unroll
            for (int kk = 0; kk < 8; kk++) {
                short8 bx[4];
                #pragma unroll
                for (int st = 0; st < 4; st++)
                    bx[st] = *(const short8*)&AA[((st * 8 + kk) * 64 + lane) * 8];
                #pragma unroll
                for (int i = 0; i < 2; i++)
                    #pragma unroll
                    for (int st = 0; st < 4; st++)
                        acc[i][st] = __builtin_amdgcn_mfma_f32_16x16x32_bf16(w2r[i][kk], bx[st], acc[i][st], 0, 0, 0);
            }
            #pragma unroll
            for (int i = 0; i < 2; i++) {
                const int nt = wv + 8 * i;
                #pragma unroll
                for (int st = 0; st < 4; st++)
                    *(short4v*)&AB[((st * 8 + (nt >> 1)) * 64 + ((((nt & 1) << 1) + (quad >> 1)) << 4) + col) * 8 + (quad & 1) * 4]
                        = pack4relu(acc[i][st]);
            }
        }
        if (it >= 1) L4B(tile - 256);    // L4(it-1): AC -> featsb
        if (it + 1 < 32) {
            LOCF(tile + 256, nxt);
            FRAG(nxt);
        }
        bar_lgkm();                  // interval-B barrier
    }
    // epilogue: L3(31) then L4(31)
    L3B();
    bar_lgkm();
    L4B(31 * 256 + blockIdx.x);
}

// ---------------- MFMA LSTM v7 (reverted): pipelined x-part + rcp-merged cell -------
// Post-barrier round-robin head (R5 structure, measured 152 us). R8's head-fold
// regressed: pre-barrier work on one wave lengthens every step; post-barrier work
// on a rotating wave hides in the ~1800-cyc slack.
__global__ __launch_bounds__(512, 1) void lstm_kernel(
    const short* __restrict__ featsb, const int* __restrict__ done,
    const float* __restrict__ h0, const float* __restrict__ c0,
    const short* __restrict__ Wtp, const float* __restrict__ bias,
    const float* __restrict__ Wa, const float* __restrict__ ba,
    const float* __restrict__ Wc, const float* __restrict__ bc,
    float* __restrict__ out)
{
    __shared__ __align__(16) short Hb[2][4 * 64 * 8];   // h frags [buf][kk2][64][8]
    __shared__ __align__(16) short HW[4 * 64 * 8];      // head B-frags
    __shared__ float Ml[T_ * 16];                       // reset masks

    const int tid = threadIdx.x;
    const int r0 = blockIdx.x * 16;
    const int grp = r0 >> 4;
    const int lane = tid & 63;
    const int wv = tid >> 6;
    const int col = lane & 15;
    const int quad = lane >> 4;
    const int u = (wv << 4) + col;

    // register-resident LSTM weights: wave wv owns n-tiles {wv, wv+8, wv+16, wv+24}
    short8 wtr[4][7];
    #pragma unroll
    for (int g = 0; g < 4; g++)
        #pragma unroll
        for (int kk = 0; kk < 7; kk++)
            wtr[g][kk] = *(const short8*)&Wtp[((size_t)((wv + 8 * g) * 7 + kk) * 64 + lane) * 8];

    // head weight B-frags -> LDS
    for (int idx = tid; idx < 4 * 64 * 8; idx += 512) {
        int j = idx & 7, L = (idx >> 3) & 63, kk2 = idx >> 9;
        int k = kk2 * 32 + ((L >> 4) << 3) + j;
        int n = L & 15;
        float v = (n < 6) ? Wa[k * 6 + n] : (n == 6 ? Wc[k] : 0.0f);
        HW[idx] = f2bf(v);
    }
    // reset masks for all T
    for (int idx = tid; idx < T_ * 16; idx += 512)
        Ml[idx] = 1.0f - (float)done[(size_t)(idx >> 4) * B_ + r0 + (idx & 15)];

    // init: c masked by done[0]; h0 UNMASKED into Hb[0] (mask applied at GEMM read)
    const int kk2h = wv >> 1;
    const int Lhi_h = ((wv & 1) << 1) | (col >> 3);
    const int jh = col & 7;
    f32x4 c;
    #pragma unroll
    for (int r = 0; r < 4; r++) {
        const int s = (quad << 2) + r;
        const float m = 1.0f - (float)done[r0 + s];
        c[r] = c0[(size_t)(r0 + s) * H_ + u] * m;
        Hb[0][(kk2h * 64 + Lhi_h * 16 + s) * 8 + jh] = f2bf(h0[(size_t)(r0 + s) * H_ + u]);
    }
    const float bi0 = bias[((wv +  0) << 4) + col];
    const float bi1 = bias[((wv +  8) << 4) + col];
    const float bi2 = bias[((wv + 16) << 4) + col];
    const float bi3 = bias[((wv + 24) << 4) + col];
    const float hb = (col < 6) ? ba[col] : (col == 6 ? bc[0] : 0.0f);

    // x prefetch banks (t-loop unrolled by 2) + x-part gate accumulators
    short8 xa[3], xb[3];
    #pragma unroll
    for (int kk = 0; kk < 3; kk++) {
        xa[kk] = *(const short8*)&featsb[FBASE(0, grp, kk) + lane * 8];
        xb[kk] = *(const short8*)&featsb[FBASE(1, grp, kk) + lane * 8];
    }
    // accX for t=0 from xa (xa regs free afterwards)
    f32x4 axA[4], axB[4];
    axA[0] = (f32x4){bi0, bi0, bi0, bi0};
    axA[1] = (f32x4){bi1, bi1, bi1, bi1};
    axA[2] = (f32x4){bi2, bi2, bi2, bi2};
    axA[3] = (f32x4){bi3, bi3, bi3, bi3};
    #pragma unroll
    for (int kk = 0; kk < 3; kk++) {
        axA[0] = __builtin_amdgcn_mfma_f32_16x16x32_bf16(xa[kk], wtr[0][kk], axA[0], 0, 0, 0);
        axA[1] = __builtin_amdgcn_mfma_f32_16x16x32_bf16(xa[kk], wtr[1][kk], axA[1], 0, 0, 0);
        axA[2] = __builtin_amdgcn_mfma_f32_16x16x32_bf16(xa[kk], wtr[2][kk], axA[2], 0, 0, 0);
        axA[3] = __builtin_amdgcn_mfma_f32_16x16x32_bf16(xa[kk], wtr[3][kk], axA[3], 0, 0, 0);
    }
    bar_lgkm();

    // STEP(t): Xload gets feats(t+2) (its regs are dead here); Xuse feeds accX for t+1.
    auto STEP = [&](int t, int cur, short8* Xload, short8* Xuse, f32x4* axT, f32x4* axN) {
        const int nxt = cur ^ 1;
        if (t + 2 < T_) {
            #pragma unroll
            for (int kk = 0; kk < 3; kk++)
                Xload[kk] = *(const short8*)&featsb[FBASE(t + 2, grp, kk) + lane * 8];
        }
        const float mcol = Ml[t * 16 + col];
        // h-part: chain depth 4, seeded from accX (computed last step)
        f32x4 acc0 = axT[0], acc1 = axT[1], acc2 = axT[2], acc3 = axT[3];
        #pragma unroll
        for (int kk2 = 0; kk2 < 4; kk2++) {
            short8 af = *(const short8*)&Hb[cur][(kk2 * 64 + lane) * 8];
            if (mcol == 0.0f) af = (short8){0,0,0,0,0,0,0,0};
            acc0 = __builtin_amdgcn_mfma_f32_16x16x32_bf16(af, wtr[0][3 + kk2], acc0, 0, 0, 0);
            acc1 = __builtin_amdgcn_mfma_f32_16x16x32_bf16(af, wtr[1][3 + kk2], acc1, 0, 0, 0);
            acc2 = __builtin_amdgcn_mfma_f32_16x16x32_bf16(af, wtr[2][3 + kk2], acc2, 0, 0, 0);
            acc3 = __builtin_amdgcn_mfma_f32_16x16x32_bf16(af, wtr[3][3 + kk2], acc3, 0, 0, 0);
        }
        // x-part for t+1: independent MFMAs, execute during the VALU section below
        f32x4 n0 = (f32x4){bi0, bi0, bi0, bi0};
        f32x4 n1 = (f32x4){bi1, bi1, bi1, bi1};
        f32x4 n2 = (f32x4){bi2, bi2, bi2, bi2};
        f32x4 n3 = (f32x4){bi3, bi3, bi3, bi3};
        #pragma unroll
        for (int kk = 0; kk < 3; kk++) {
            n0 = __builtin_amdgcn_mfma_f32_16x16x32_bf16(Xuse[kk], wtr[0][kk], n0, 0, 0, 0);
            n1 = __builtin_amdgcn_mfma_f32_16x16x32_bf16(Xuse[kk], wtr[1][kk], n1, 0, 0, 0);
            n2 = __builtin_amdgcn_mfma_f32_16x16x32_bf16(Xuse[kk], wtr[2][kk], n2, 0, 0, 0);
            n3 = __builtin_amdgcn_mfma_f32_16x16x32_bf16(Xuse[kk], wtr[3][kk], n3, 0, 0, 0);
        }
        axN[0] = n0; axN[1] = n1; axN[2] = n2; axN[3] = n3;
        // cell update: rcp-merged form, 5 exp2 + 2 rcp per element
        float4 mn = {1.f, 1.f, 1.f, 1.f};
        if (t < T_ - 1) mn = *(const float4*)&Ml[(t + 1) * 16 + (quad << 2)];
        #pragma unroll
        for (int r = 0; r < 4; r++) {
            const float ei = __builtin_amdgcn_exp2f(-acc0[r]);     // i gate
            const float ef = __builtin_amdgcn_exp2f(-acc1[r]);     // f gate
            const float eg = __builtin_amdgcn_exp2f(-acc2[r]);     // g gate (2x pre-scale)
            const float eo = __builtin_amdgcn_exp2f(-acc3[r]);     // o gate
            const float Ai = 1.0f + ei, Bf = 1.0f + ef;
            const float Gg = 1.0f + eg, Do = 1.0f + eo;
            const float AG = Ai * Gg;
            const float num = fmaf(c[r], AG, (1.0f - eg) * Bf);
            const float cn = num * __builtin_amdgcn_rcpf(AG * Bf);
            const float et = __builtin_amdgcn_exp2f(-2.0f * L2E * cn);
            const float h = (1.0f - et) * __builtin_amdgcn_rcpf(Do * (1.0f + et));
            c[r] = cn * ((&mn.x)[r]);
            Hb[nxt][(kk2h * 64 + Lhi_h * 16 + (quad << 2) + r) * 8 + jh] = f2bf(h);
        }
        bar_lgkm();

        // round-robin heads: wave (t&7) computes step t's heads from Hb[nxt];
        // the other 7 waves race ahead into the next step's main phase.
        if (wv == (t & 7)) {
            f32x4 ha = {hb, hb, hb, hb};
            #pragma unroll
            for (int kk2 = 0; kk2 < 4; kk2++) {
                const short8 hf = *(const short8*)&Hb[nxt][(kk2 * 64 + lane) * 8];
                const short8 wf = *(const short8*)&HW[(kk2 * 64 + lane) * 8];
                ha = __builtin_amdgcn_mfma_f32_16x16x32_bf16(hf, wf, ha, 0, 0, 0);
            }
            if (col < 7) {
                #pragma unroll
                for (int r = 0; r < 4; r++) {
                    const int s = (quad << 2) + r;
                    out[((size_t)t * B_ + r0 + s) * 7 + col] = ha[r];
                }
            }
        }
    };

    for (int t = 0; t < T_; t += 2) {
        STEP(t,     0, xa, xb, axA, axB);
        STEP(t + 1, 1, xb, xa, axB, axA);
    }
}

extern "C" void kernel_launch(void* const* d_in, const int* in_sizes, int n_in,
                              void* d_out, int out_size, void* d_ws, size_t ws_size,
                              hipStream_t stream) {
    const float* image    = (const float*)d_in[0];
    const float* location = (const float*)d_in[1];
    const float* energy   = (const float*)d_in[2];
    const int*   done     = (const int*)d_in[3];
    const float* h0       = (const float*)d_in[4];
    const float* c0       = (const float*)d_in[5];
    const float* W1 = (const float*)d_in[6];   const float* b1 = (const float*)d_in[7];
    const float* W2 = (const float*)d_in[8];   const float* b2 = (const float*)d_in[9];
    const float* W3 = (const float*)d_in[10];  const float* b3 = (const float*)d_in[11];
    const float* W4 = (const float*)d_in[12];  const float* b4 = (const float*)d_in[13];
    const float* Wl = (const float*)d_in[14];  const float* bl = (const float*)d_in[15];
    const float* We = (const float*)d_in[16];  const float* be = (const float*)d_in[17];
    const float* Wih = (const float*)d_in[18]; const float* Whh = (const float*)d_in[19];
    const float* bih = (const float*)d_in[20]; const float* bhh = (const float*)d_in[21];
    const float* Wa = (const float*)d_in[22];  const float* ba = (const float*)d_in[23];
    const float* Wc = (const float*)d_in[24];  const float* bc = (const float*)d_in[25];

    char* ws = (char*)d_ws;
    short* Wtp   = (short*)ws;                     // 229376 B
    float* bias  = (float*)(ws + 229376);          // 2048 B
    short* W1p   = (short*)(ws + 231424);          // 16384 B
    short* W2p   = (short*)(ws + 247808);          // 131072 B
    short* W3p   = (short*)(ws + 378880);          // 65536 B
    short* W4p   = (short*)(ws + 444416);          // 8192 B
    short* featsb = (short*)(ws + 452608);         // N*96 bf16 (frag order)
    float* out   = (float*)d_out;

    prep_kernel<<<882, 256, 0, stream>>>(Wih, Whh, bih, bhh, W1, W2, W3, W4,
                                         Wtp, bias, W1p, W2p, W3p, W4p);
    enc_kernel<<<256, 512, 0, stream>>>(image, location, energy, Wl, bl, We, be,
                                        W1p, b1, W2p, b2, W3p, b3, W4p, b4, featsb);
    lstm_kernel<<<B_ / 16, 512, 0, stream>>>(featsb, done, h0, c0, Wtp, bias,
                                             Wa, ba, Wc, bc, out);
}